// Round 1
// baseline (282.359 us; speedup 1.0000x reference)
//
#include <hip/hip_runtime.h>

#define N_NODES 100000
#define NFEAT 256
#define NHID 128
#define NCLASS 8

#define BSH 8                          // bucket = dst >> 8 (256 nodes/bucket)
#define BUCK 256
#define NBUCK ((N_NODES + BUCK - 1) / BUCK)   // 391
#define CAPB 5120                      // fixed per-bucket region: mean 4096 + 16 sigma
#define NBLK1 512                      // scatter blocks
#define CHMAX 3200                     // >= ceil(1.6e6/512)=3125 rounded to 3128

// ---------------------------------------------------------------------------
// K0: zero deg, init per-bucket global cursors to b*CAPB, precompute
// Wc = W1 @ Wfc (folded since there is no activation between conv and fc)
// and cvec = b1 @ Wfc + bfc.
__global__ __launch_bounds__(512) void init_kernel(const float* __restrict__ W1,
        const float* __restrict__ b1, const float* __restrict__ Wfc,
        const float* __restrict__ bfc, float* __restrict__ WcT,
        float* __restrict__ cvec, int* __restrict__ deg, int* __restrict__ gcur) {
    int tid = threadIdx.x;
    if (blockIdx.x == 0) {
        __shared__ float wfs[NHID * NCLASS];
        __shared__ float bs[NHID];
        for (int i = tid; i < NHID * NCLASS; i += 512) wfs[i] = Wfc[i];
        if (tid < NHID) bs[tid] = b1[tid];
        __syncthreads();
        if (tid < NFEAT) {
            float acc[NCLASS] = {};
            for (int h = 0; h < NHID; h++) {
                float w = W1[tid * NHID + h];
                #pragma unroll
                for (int c = 0; c < NCLASS; c++) acc[c] += w * wfs[h * NCLASS + c];
            }
            #pragma unroll
            for (int c = 0; c < NCLASS; c++) WcT[c * NFEAT + tid] = acc[c];
        }
        if (tid < NCLASS) {
            float a = bfc[tid];
            for (int h = 0; h < NHID; h++) a += bs[h] * wfs[h * NCLASS + tid];
            cvec[tid] = a;
        }
    } else {
        int i = (blockIdx.x - 1) * 512 + tid;
        if (i < N_NODES) deg[i] = 0;
        if (blockIdx.x == 1 && tid < NBUCK) gcur[tid] = tid * CAPB;
    }
}

// ---------------------------------------------------------------------------
// K1: single edge pass. Per block: LDS bucket histogram + global deg atomics,
// pairwise scan of 392 bucket counts, atomic range reservation in gcur,
// in-LDS counting sort of the chunk (packed src<<8|local_dst), then
// coalesced bucket-run writeout to ebufP. Intra-bucket order is irrelevant
// (gather kernel re-sorts), so no stable block ordering is needed.
__global__ __launch_bounds__(256) void scat_kernel(const int* __restrict__ esrc,
        const int* __restrict__ edst, int* __restrict__ deg, int* __restrict__ gcur,
        int* __restrict__ ebufP, int chunk, int nE) {
    __shared__ int h[NBUCK + 1];          // counts, then reused as global bases
    __shared__ int lbase[NBUCK + 1];      // local (in-chunk) exclusive bases
    __shared__ int lcur[NBUCK];
    __shared__ int ssc[256];
    __shared__ int pk[CHMAX];
    __shared__ unsigned short bk[CHMAX];
    int tid = threadIdx.x;
    for (int i = tid; i < NBUCK + 1; i += 256) h[i] = 0;
    __syncthreads();
    int e0 = blockIdx.x * chunk;
    int e1 = min(e0 + chunk, nE);
    int cntE = e1 - e0;
    // pass 1: histogram + per-node degree
    for (int e = e0 + tid * 4; e + 3 < e1; e += 1024) {
        int4 d = *(const int4*)&edst[e];
        atomicAdd(&h[d.x >> BSH], 1); atomicAdd(&h[d.y >> BSH], 1);
        atomicAdd(&h[d.z >> BSH], 1); atomicAdd(&h[d.w >> BSH], 1);
        atomicAdd(&deg[d.x], 1); atomicAdd(&deg[d.y], 1);
        atomicAdd(&deg[d.z], 1); atomicAdd(&deg[d.w], 1);
    }
    int full = e0 + (cntE & ~3);
    if (full + tid < e1) {
        int d = edst[full + tid];
        atomicAdd(&h[d >> BSH], 1);
        atomicAdd(&deg[d], 1);
    }
    __syncthreads();
    // scan 392 entries: each thread owns slots (2t, 2t+1)
    int i0 = 2 * tid, i1 = 2 * tid + 1;
    int v0 = (i0 <= NBUCK) ? h[i0] : 0;
    int v1 = (i1 <= NBUCK) ? h[i1] : 0;
    ssc[tid] = v0 + v1;
    __syncthreads();
    for (int o = 1; o < 256; o <<= 1) {
        int u = (tid >= o) ? ssc[tid - o] : 0;
        __syncthreads(); ssc[tid] += u; __syncthreads();
    }
    int ex = ssc[tid] - (v0 + v1);
    if (i0 <= NBUCK) lbase[i0] = ex;
    if (i1 <= NBUCK) lbase[i1] = ex + v0;
    __syncthreads();
    // reserve contiguous global ranges, set local cursors
    for (int b = tid; b < NBUCK; b += 256) {
        int c = h[b];
        int gb = c ? atomicAdd(&gcur[b], c) : 0;
        h[b] = gb;                        // reuse as global base
        lcur[b] = lbase[b];
    }
    __syncthreads();
    // pass 2: re-read chunk (L2-hot) and counting-sort into LDS
    for (int e = e0 + tid * 4; e + 3 < e1; e += 1024) {
        int4 s = *(const int4*)&esrc[e];
        int4 d = *(const int4*)&edst[e];
        int b0 = d.x >> BSH, b1_ = d.y >> BSH, b2 = d.z >> BSH, b3 = d.w >> BSH;
        int p0 = atomicAdd(&lcur[b0], 1);
        int p1 = atomicAdd(&lcur[b1_], 1);
        int p2 = atomicAdd(&lcur[b2], 1);
        int p3 = atomicAdd(&lcur[b3], 1);
        pk[p0] = (s.x << BSH) | (d.x & (BUCK - 1)); bk[p0] = (unsigned short)b0;
        pk[p1] = (s.y << BSH) | (d.y & (BUCK - 1)); bk[p1] = (unsigned short)b1_;
        pk[p2] = (s.z << BSH) | (d.z & (BUCK - 1)); bk[p2] = (unsigned short)b2;
        pk[p3] = (s.w << BSH) | (d.w & (BUCK - 1)); bk[p3] = (unsigned short)b3;
    }
    if (full + tid < e1) {
        int s = esrc[full + tid], d = edst[full + tid];
        int b = d >> BSH;
        int p = atomicAdd(&lcur[b], 1);
        pk[p] = (s << BSH) | (d & (BUCK - 1)); bk[p] = (unsigned short)b;
    }
    __syncthreads();
    // coalesced writeout: position i of the sorted chunk goes to
    // global_base[bucket(i)] + (i - local_base[bucket(i)])
    for (int i = tid; i < cntE; i += 256) {
        int b = bk[i];
        ebufP[h[b] + (i - lbase[b])] = pk[i];
    }
}

// ---------------------------------------------------------------------------
// Kz: Zs[i][c] = dot(X[i], WcT[c]) * rsqrt(deg[i]+1).  Wave = 8 rows; 8
// lanes/row own 32 features in 8 float4 regs; WcT in LDS; shfl_xor reduce.
__global__ __launch_bounds__(256) void z_kernel(const float* __restrict__ X,
                                                const float* __restrict__ WcT,
                                                const int* __restrict__ deg,
                                                float* __restrict__ Zs, int n) {
    __shared__ float4 wlds[NCLASS * 64];
    int tid = threadIdx.x;
    #pragma unroll
    for (int i = tid; i < NCLASS * 64; i += 256)
        wlds[i] = ((const float4*)WcT)[i];
    __syncthreads();

    const int lane = tid & 63;
    const int sub  = lane & 7;
    const int rsub = lane >> 3;
    const int wid  = (blockIdx.x * 256 + tid) >> 6;
    const int nw   = (gridDim.x * 256) >> 6;
    const int ngroups = (n + 7) >> 3;

    for (int g = wid; g < ngroups; g += nw) {
        int row = g * 8 + rsub;
        bool ok = row < n;
        int r = ok ? row : (n - 1);
        const float4* xr = (const float4*)(X + (long)r * NFEAT);
        float4 xv[8];
        #pragma unroll
        for (int k = 0; k < 8; k++) xv[k] = xr[sub + 8 * k];

        float res = 0.f;
        #pragma unroll
        for (int c = 0; c < NCLASS; c++) {
            float s = 0.f;
            #pragma unroll
            for (int k = 0; k < 8; k++) {
                float4 w = wlds[c * 64 + sub + 8 * k];
                s += xv[k].x * w.x + xv[k].y * w.y + xv[k].z * w.z + xv[k].w * w.w;
            }
            s += __shfl_xor(s, 1);
            s += __shfl_xor(s, 2);
            s += __shfl_xor(s, 4);
            if (sub == c) res = s;
        }
        if (ok) {
            float dv = rsqrtf((float)(deg[row] + 1));
            Zs[(long)row * NCLASS + sub] = res * dv;
        }
    }
}

// ---------------------------------------------------------------------------
// Kg: fused in-LDS counting sort + register-accumulate gather per bucket.
// Bucket b occupies ebufP[b*CAPB .. gcur[b]).
__global__ __launch_bounds__(512) void sort_gather_kernel(
        const float* __restrict__ Zs,
        const int* __restrict__ ebufP,
        const int* __restrict__ gcur,
        const float* __restrict__ cvec,
        float* __restrict__ out, int n) {
    __shared__ int cnt[BUCK];          // counts, then cursors
    __shared__ int off[BUCK + 1];
    __shared__ int ss[BUCK];
    __shared__ int sorted[CAPB];
    int b = blockIdx.x, tid = threadIdx.x;
    int base = b * CAPB;
    int end = min(gcur[b], base + CAPB);   // clamp for memory safety
    const float4* Zs4 = (const float4*)Zs;
    float4 c0v = ((const float4*)cvec)[0];
    float4 c1v = ((const float4*)cvec)[1];

    if (tid < BUCK) cnt[tid] = 0;
    __syncthreads();
    int a0 = min((base + 3) & ~3, end);
    if (base + tid < a0) atomicAdd(&cnt[ebufP[base + tid] & (BUCK - 1)], 1);
    for (int e = a0 + tid * 4; e + 3 < end; e += 2048) {
        int4 p = *(const int4*)&ebufP[e];
        atomicAdd(&cnt[p.x & (BUCK - 1)], 1);
        atomicAdd(&cnt[p.y & (BUCK - 1)], 1);
        atomicAdd(&cnt[p.z & (BUCK - 1)], 1);
        atomicAdd(&cnt[p.w & (BUCK - 1)], 1);
    }
    int full = a0 + ((end - a0) & ~3);
    if (full + tid < end) atomicAdd(&cnt[ebufP[full + tid] & (BUCK - 1)], 1);
    __syncthreads();

    int t = (tid < BUCK) ? cnt[tid] : 0;
    if (tid < BUCK) ss[tid] = t;
    __syncthreads();
    for (int o = 1; o < BUCK; o <<= 1) {
        int u = 0;
        if (tid < BUCK && tid >= o) u = ss[tid - o];
        __syncthreads();
        if (tid < BUCK) ss[tid] += u;
        __syncthreads();
    }
    if (tid < BUCK) {
        off[tid] = ss[tid] - t;
        cnt[tid] = ss[tid] - t;     // cursor
        if (tid == BUCK - 1) off[BUCK] = ss[tid];
    }
    __syncthreads();

    if (base + tid < a0) {
        int p = ebufP[base + tid];
        int slot = atomicAdd(&cnt[p & (BUCK - 1)], 1);
        sorted[slot] = p >> BSH;
    }
    for (int e = a0 + tid * 4; e + 3 < end; e += 2048) {
        int4 p = *(const int4*)&ebufP[e];
        int s0 = atomicAdd(&cnt[p.x & (BUCK - 1)], 1);
        int s1 = atomicAdd(&cnt[p.y & (BUCK - 1)], 1);
        int s2 = atomicAdd(&cnt[p.z & (BUCK - 1)], 1);
        int s3 = atomicAdd(&cnt[p.w & (BUCK - 1)], 1);
        sorted[s0] = p.x >> BSH;
        sorted[s1] = p.y >> BSH;
        sorted[s2] = p.z >> BSH;
        sorted[s3] = p.w >> BSH;
    }
    if (full + tid < end) {
        int p = ebufP[full + tid];
        int slot = atomicAdd(&cnt[p & (BUCK - 1)], 1);
        sorted[slot] = p >> BSH;
    }
    __syncthreads();

    int li = tid >> 1;
    int hh = tid & 1;
    int node = (b << BSH) + li;
    if (node < n) {
        int k0 = off[li], k1 = off[li + 1];
        float4 a = Zs4[node * 2 + hh];                    // self-loop
        int k = k0;
        for (; k + 1 < k1; k += 2) {
            int s0 = sorted[k], s1 = sorted[k + 1];
            float4 z0 = Zs4[s0 * 2 + hh];
            float4 z1 = Zs4[s1 * 2 + hh];
            a.x += z0.x + z1.x; a.y += z0.y + z1.y;
            a.z += z0.z + z1.z; a.w += z0.w + z1.w;
        }
        if (k < k1) {
            float4 z = Zs4[sorted[k] * 2 + hh];
            a.x += z.x; a.y += z.y; a.z += z.z; a.w += z.w;
        }
        float dd = rsqrtf((float)(k1 - k0 + 1));          // local degree + self
        float4 cv = hh ? c1v : c0v;
        float4 o;
        o.x = a.x * dd + cv.x; o.y = a.y * dd + cv.y;
        o.z = a.z * dd + cv.z; o.w = a.w * dd + cv.w;
        ((float4*)out)[node * 2 + hh] = o;
    }
}

// ---------------------------------------------------------------------------
extern "C" void kernel_launch(void* const* d_in, const int* in_sizes, int n_in,
                              void* d_out, int out_size, void* d_ws, size_t ws_size,
                              hipStream_t stream) {
    const float* x    = (const float*)d_in[0];   // [N, 256]
    const int*   eidx = (const int*)d_in[1];     // [2, E] (int32 — JAX x64 disabled)
    const float* W1   = (const float*)d_in[2];   // [256, 128]
    const float* b1   = (const float*)d_in[3];   // [128]
    const float* Wfc  = (const float*)d_in[4];   // [128, 8]
    const float* bfc  = (const float*)d_in[5];   // [8]
    float* out = (float*)d_out;

    const int N = N_NODES;
    const int E = in_sizes[1] / 2;

    const int* esrc = eidx;
    const int* edst = eidx + E;

    // workspace layout (~11.6 MB); every region written before read.
    float* Zs    = (float*)d_ws;                     // 8N floats (16B-aligned)
    float* cvec  = Zs + (long)8 * N;                 // 8   (byte 3.2e6, 16B-aligned)
    float* WcT   = cvec + 8;                         // 2048
    int*   deg   = (int*)(WcT + NCLASS * NFEAT);     // N
    int*   gcur  = deg + N;                          // NBUCK (+pad)
    int*   ebufP = gcur + 392;                       // NBUCK*CAPB (16B-aligned: 902448*4 % 16 == 0)

    const int chunk = (((E + NBLK1 - 1) / NBLK1) + 3) & ~3;   // 3128 <= CHMAX

    init_kernel<<<1 + (N + 511) / 512, 512, 0, stream>>>(W1, b1, Wfc, bfc, WcT, cvec, deg, gcur);
    scat_kernel<<<NBLK1, 256, 0, stream>>>(esrc, edst, deg, gcur, ebufP, chunk, E);
    z_kernel<<<1563, 256, 0, stream>>>(x, WcT, deg, Zs, N);
    sort_gather_kernel<<<NBUCK, 512, 0, stream>>>(Zs, ebufP, gcur, cvec, out, N);
}